// Round 4
// baseline (247234.790 us; speedup 1.0000x reference)
//
#include <hip/hip_runtime.h>
#include <math.h>

// ODE-RNN, T=8192 steps, IN=512, H=1024, OUT=256, 4 euler substeps/step.
// Persistent-kernel, barrier-free epoch-tagged dataflow:
//   every shared vector element is one 8-byte agent-scope atomic
//   (epoch<<32 | f32 bits). Readers poll until the tag matches.
// WAR-safe: epoch e+1 of any slot is only produced after its writer consumed
// the FULL successor vector, each element of which required its producer to
// have fully read epoch e (full-read dependency ring).

#define TSTEPS 8192
#define INP    512
#define HDIM   1024
#define OUTD   256
#define NWG    64
#define BLK    256
#define RPW    (HDIM / NWG)      // 16 rows per WG for H-sized vectors
#define TPR    (BLK / RPW)       // 16 threads per row
#define SPT    (HDIM / BLK)      // 4 staged values per thread

typedef unsigned long long u64;
typedef unsigned int u32;

__device__ __forceinline__ u64 aload(u64* p) {
    return __hip_atomic_load(p, __ATOMIC_RELAXED, __HIP_MEMORY_SCOPE_AGENT);
}
__device__ __forceinline__ void astore(u64* p, u64 v) {
    __hip_atomic_store(p, v, __ATOMIC_RELAXED, __HIP_MEMORY_SCOPE_AGENT);
}
__device__ __forceinline__ u64 pack(u32 tag, float f) {
    return ((u64)tag << 32) | (u64)__float_as_uint(f);
}

__global__ __launch_bounds__(BLK)
void ode_rnn_persistent(
    const float* __restrict__ t,    const float* __restrict__ x,
    const float* __restrict__ W_in, const float* __restrict__ b_in,
    const float* __restrict__ W_h,  const float* __restrict__ b_h,
    const float* __restrict__ W_h2, const float* __restrict__ b_h2,
    const float* __restrict__ W_f1, const float* __restrict__ b_f1,
    const float* __restrict__ W_f2, const float* __restrict__ b_f2,
    const float* __restrict__ W_dec,const float* __restrict__ b_dec,
    float* __restrict__ out,
    u64* hq, u64* uq, u64* aq)
{
    __shared__ __align__(16) float lds[HDIM];
    const int tid = threadIdx.x;
    const int wg  = blockIdx.x;
    const int seg = tid & (TPR - 1);          // 0..15 within a row group
    const int row = wg * RPW + (tid >> 4);    // owned output row (H-vectors)

    float h_own = 0.0f;                       // h[row]; live in seg==0 lanes
    u32 eh = 0, eu = 0, ea = 0;               // epochs, uniform across threads

    // Poll the full vector at `tag` into LDS. Leading sync protects the
    // previous phase's LDS readers; trailing sync publishes to this WG.
    auto stage = [&](u64* q, u32 tag) {
        __syncthreads();
        #pragma unroll
        for (int k = 0; k < SPT; ++k) {
            const int idx = tid + k * BLK;
            u64 v = aload(&q[idx]);
            while ((u32)(v >> 32) != tag) { v = aload(&q[idx]); }
            lds[idx] = __uint_as_float((u32)v);
        }
        __syncthreads();
    };

    // Partial dot of one weight row (K=HDIM) against lds; no reduction.
    // Element map j*64 + seg*4: coalesced global float4s, <=2-way LDS alias.
    auto dotPart = [&](const float* Wrow) {
        float acc = 0.0f;
        #pragma unroll
        for (int j = 0; j < 16; ++j) {
            const int idx = j * 64 + seg * 4;
            const float4 w = *reinterpret_cast<const float4*>(Wrow + idx);
            const float4 v = *reinterpret_cast<const float4*>(lds + idx);
            acc = fmaf(w.x, v.x, acc); acc = fmaf(w.y, v.y, acc);
            acc = fmaf(w.z, v.z, acc); acc = fmaf(w.w, v.w, acc);
        }
        return acc;
    };
    auto reduce16 = [&](float acc) {
        #pragma unroll
        for (int off = TPR / 2; off; off >>= 1)
            acc += __shfl_down(acc, off, TPR);
        return acc;   // valid on seg==0
    };

    #pragma unroll 1
    for (int i = 1; i < TSTEPS; ++i) {
        const float dt = (t[i] - t[i - 1]) * 0.25f;   // /NSUB
        const float* xi = x + (size_t)i * INP;

        // ---- 4 Euler substeps: h += dt*(Wf2 @ tanh(Wf1 @ h + bf1) + bf2)
        #pragma unroll 1
        for (int s = 0; s < 4; ++s) {
            stage(hq, eh);                                   // full h
            float d1 = reduce16(dotPart(W_f1 + (size_t)row * HDIM));
            ++eu;
            if (seg == 0)
                astore(&uq[row], pack(eu, tanhf(d1 + b_f1[row])));

            stage(uq, eu);                                   // full u
            float d2 = reduce16(dotPart(W_f2 + (size_t)row * HDIM));
            ++eh;
            if (seg == 0) {
                h_own = fmaf(dt, d2 + b_f2[row], h_own);
                astore(&hq[row], pack(eh, h_own));
            }
        }

        // ---- RNN cell: a = tanh(Wh@h + Win@x_i + b_in + b_h)
        stage(hq, eh);                                       // full h
        {
            float acc = dotPart(W_h + (size_t)row * HDIM);
            const float* Wir = W_in + (size_t)row * INP;
            #pragma unroll
            for (int j = 0; j < 8; ++j) {
                const int idx = j * 64 + seg * 4;
                const float4 w = *reinterpret_cast<const float4*>(Wir + idx);
                const float4 v = *reinterpret_cast<const float4*>(xi + idx);
                acc = fmaf(w.x, v.x, acc); acc = fmaf(w.y, v.y, acc);
                acc = fmaf(w.z, v.z, acc); acc = fmaf(w.w, v.w, acc);
            }
            acc = reduce16(acc);
            ++ea;
            if (seg == 0)
                astore(&aq[row], pack(ea, tanhf(acc + b_in[row] + b_h[row])));
        }

        // ---- h = tanh(Wh2 @ a + bh2)
        stage(aq, ea);                                       // full a
        {
            float d3 = reduce16(dotPart(W_h2 + (size_t)row * HDIM));
            ++eh;
            if (seg == 0) {
                h_own = tanhf(d3 + b_h2[row]);
                astore(&hq[row], pack(eh, h_own));
            }
        }
    }

    // ---- decode: out = W_dec @ h_T + b_dec   (256 rows, 4 per WG)
    stage(hq, eh);
    {
        const int rl2  = tid >> 6;            // 0..3
        const int s2   = tid & 63;
        const int orow = wg * (OUTD / NWG) + rl2;
        const float* Wdr = W_dec + (size_t)orow * HDIM;
        float acc = 0.0f;
        #pragma unroll
        for (int j = 0; j < 4; ++j) {
            const int idx = j * 256 + s2 * 4;
            const float4 w = *reinterpret_cast<const float4*>(Wdr + idx);
            const float4 v = *reinterpret_cast<const float4*>(lds + idx);
            acc = fmaf(w.x, v.x, acc); acc = fmaf(w.y, v.y, acc);
            acc = fmaf(w.z, v.z, acc); acc = fmaf(w.w, v.w, acc);
        }
        #pragma unroll
        for (int off = 32; off; off >>= 1)
            acc += __shfl_down(acc, off, 64);
        if (s2 == 0) out[orow] = acc + b_dec[orow];
    }
}

extern "C" void kernel_launch(void* const* d_in, const int* in_sizes, int n_in,
                              void* d_out, int out_size, void* d_ws, size_t ws_size,
                              hipStream_t stream) {
    const float* t     = (const float*)d_in[0];
    const float* x     = (const float*)d_in[1];
    const float* W_in  = (const float*)d_in[2];
    const float* b_in  = (const float*)d_in[3];
    const float* W_h   = (const float*)d_in[4];
    const float* b_h   = (const float*)d_in[5];
    const float* W_h2  = (const float*)d_in[6];
    const float* b_h2  = (const float*)d_in[7];
    const float* W_f1  = (const float*)d_in[8];
    const float* b_f1  = (const float*)d_in[9];
    const float* W_f2  = (const float*)d_in[10];
    const float* b_f2  = (const float*)d_in[11];
    const float* W_dec = (const float*)d_in[12];
    const float* b_dec = (const float*)d_in[13];
    float* out = (float*)d_out;

    unsigned char* ws = (unsigned char*)d_ws;
    u64* hq = (u64*)(ws);            // 1024 * 8B
    u64* uq = (u64*)(ws + 8192);     // 1024 * 8B
    u64* aq = (u64*)(ws + 16384);    // 1024 * 8B

    // h starts at zero with epoch tag 0; u/a tags 0 are never expected
    // before their first write (first expected epoch is 1). Must re-init
    // every call: harness does not re-poison ws between graph replays.
    hipMemsetAsync(d_ws, 0, 3 * 8192, stream);

    ode_rnn_persistent<<<dim3(NWG), dim3(BLK), 0, stream>>>(
        t, x, W_in, b_in, W_h, b_h, W_h2, b_h2,
        W_f1, b_f1, W_f2, b_f2, W_dec, b_dec,
        out, hq, uq, aq);
}

// Round 5
// 100533.160 us; speedup vs baseline: 2.4592x; 2.4592x over previous
//
#include <hip/hip_runtime.h>
#include <math.h>

// ODE-RNN, T=8192, IN=512, H=1024, OUT=256, 4 euler substeps/step.
// R4: pre-activation-space recurrence cuts cross-WG handoffs 10 -> 6 per step.
//   z = W_f1 h + b_f1,  y = W_h h,  M = W_f1 W_f2,  P = W_h W_f2 (precomputed)
//   substep: u = tanh(z); z += dt(M u + c1); y += dt(P u + c2)   [1 broadcast]
//   cell:    a = tanh(y4 + W_in x + b_in + b_h)                  [1 broadcast]
//            h' = tanh(W_h2 a + b_h2)                            [1 broadcast]
//            z = W_f1 h' + b_f1; y = W_h h'   (reset -> no error accumulation)
// Handoff = epoch-tagged 8B agent atomics (tag<<32 | f32). Concurrent 4-slot
// poll; weight rows register-prefetched before the poll (hidden under spin).
// WAR-safe: every queue has reuse distance >= 2 full-broadcast consumptions
// (u alternates QA/QB), so a slot can't advance past a waiting reader.

#define TSTEPS 8192
#define INP    512
#define HDIM   1024
#define OUTD   256
#define NWG    64
#define BLK    256

typedef unsigned long long u64;
typedef unsigned int u32;

__device__ __forceinline__ u64 aload(u64* p) {
    return __hip_atomic_load(p, __ATOMIC_RELAXED, __HIP_MEMORY_SCOPE_AGENT);
}
__device__ __forceinline__ void astore(u64* p, u64 v) {
    __hip_atomic_store(p, v, __ATOMIC_RELAXED, __HIP_MEMORY_SCOPE_AGENT);
}
__device__ __forceinline__ u64 pack(u32 tag, float f) {
    return ((u64)tag << 32) | (u64)__float_as_uint(f);
}

// ---------------- precompute: C = A @ B, 1024x1024x1024 fp32 ----------------
__global__ __launch_bounds__(256)
void mm1024(const float* __restrict__ A, const float* __restrict__ B,
            float* __restrict__ C) {
    __shared__ float As[64][17];
    __shared__ float Bs[16][65];
    const int tid = threadIdx.x;
    const int tx = tid & 15, ty = tid >> 4;
    const int r0 = blockIdx.y * 64, c0 = blockIdx.x * 64;
    float acc[4][4] = {};
    for (int k0 = 0; k0 < HDIM; k0 += 16) {
        const int ar = tid >> 2, ac = (tid & 3) * 4;
        const float4 av = *reinterpret_cast<const float4*>(
            A + (size_t)(r0 + ar) * HDIM + k0 + ac);
        As[ar][ac] = av.x; As[ar][ac + 1] = av.y;
        As[ar][ac + 2] = av.z; As[ar][ac + 3] = av.w;
        const int br = tid >> 4, bc = (tid & 15) * 4;
        const float4 bv = *reinterpret_cast<const float4*>(
            B + (size_t)(k0 + br) * HDIM + c0 + bc);
        Bs[br][bc] = bv.x; Bs[br][bc + 1] = bv.y;
        Bs[br][bc + 2] = bv.z; Bs[br][bc + 3] = bv.w;
        __syncthreads();
        #pragma unroll
        for (int kk = 0; kk < 16; ++kk) {
            float a[4], b[4];
            #pragma unroll
            for (int i2 = 0; i2 < 4; ++i2) a[i2] = As[ty * 4 + i2][kk];
            #pragma unroll
            for (int j2 = 0; j2 < 4; ++j2) b[j2] = Bs[kk][tx * 4 + j2];
            #pragma unroll
            for (int i2 = 0; i2 < 4; ++i2)
                #pragma unroll
                for (int j2 = 0; j2 < 4; ++j2)
                    acc[i2][j2] = fmaf(a[i2], b[j2], acc[i2][j2]);
        }
        __syncthreads();
    }
    #pragma unroll
    for (int i2 = 0; i2 < 4; ++i2)
        #pragma unroll
        for (int j2 = 0; j2 < 4; ++j2)
            C[(size_t)(r0 + ty * 4 + i2) * HDIM + c0 + tx * 4 + j2] = acc[i2][j2];
}

// ---------------------------- persistent kernel -----------------------------
__global__ __launch_bounds__(BLK, 1)
void ode_rnn_persistent(
    const float* __restrict__ t,    const float* __restrict__ x,
    const float* __restrict__ W_in, const float* __restrict__ b_in,
    const float* __restrict__ W_h,  const float* __restrict__ b_h,
    const float* __restrict__ W_h2, const float* __restrict__ b_h2,
    const float* __restrict__ W_f1, const float* __restrict__ b_f1,
    const float* __restrict__ b_f2,
    const float* __restrict__ W_dec, const float* __restrict__ b_dec,
    const float* __restrict__ Mw,   const float* __restrict__ Pw,
    float* __restrict__ out,
    u64* QA, u64* QB, u64* QC, u64* QD)
{
    __shared__ __align__(16) float lds[HDIM];
    const int tid = threadIdx.x;
    const int wg  = blockIdx.x;
    const int seg = tid & 15;                 // 16 lanes per row
    const int row = wg * 16 + (tid >> 4);     // owned row

    // Poll full vector at epoch `tag` into LDS; all 4 owned slots polled
    // concurrently (one fabric round trip per sweep, not four).
    auto stage = [&](u64* q, u32 tag) {
        __syncthreads();
        const int i0 = tid, i1 = tid + 256, i2 = tid + 512, i3 = tid + 768;
        u64 v0, v1, v2, v3;
        for (;;) {
            v0 = aload(q + i0); v1 = aload(q + i1);
            v2 = aload(q + i2); v3 = aload(q + i3);
            const bool ok = ((u32)(v0 >> 32) == tag) & ((u32)(v1 >> 32) == tag) &
                            ((u32)(v2 >> 32) == tag) & ((u32)(v3 >> 32) == tag);
            if (ok) break;
        }
        lds[i0] = __uint_as_float((u32)v0); lds[i1] = __uint_as_float((u32)v1);
        lds[i2] = __uint_as_float((u32)v2); lds[i3] = __uint_as_float((u32)v3);
        __syncthreads();
    };

    auto pref16 = [&](float4* w, const float* Wbase) {
        const float4* p = reinterpret_cast<const float4*>(Wbase + (size_t)row * HDIM);
        #pragma unroll
        for (int j = 0; j < 16; ++j) w[j] = p[j * 16 + seg];
    };
    auto dot16 = [&](const float4* w) {
        float a = 0.f;
        #pragma unroll
        for (int j = 0; j < 16; ++j) {
            const float4 v = *reinterpret_cast<const float4*>(lds + j * 64 + seg * 4);
            a = fmaf(w[j].x, v.x, a); a = fmaf(w[j].y, v.y, a);
            a = fmaf(w[j].z, v.z, a); a = fmaf(w[j].w, v.w, a);
        }
        return a;
    };
    auto reduce16 = [&](float a) {
        #pragma unroll
        for (int off = 8; off; off >>= 1) a += __shfl_down(a, off, 16);
        return a;
    };

    const float bf1_r = b_f1[row];
    const float bih_r = b_in[row] + b_h[row];
    const float bh2_r = b_h2[row];

    // c1 = (W_f1 @ b_f2)[row], c2 = (W_h @ b_f2)[row]  — once, off critical path
    float c1_own, c2_own;
    {
        #pragma unroll
        for (int k = 0; k < 4; ++k) lds[tid + k * 256] = b_f2[tid + k * 256];
        __syncthreads();
        float4 w[16];
        pref16(w, W_f1); c1_own = reduce16(dot16(w));
        pref16(w, W_h);  c2_own = reduce16(dot16(w));
    }

    float z_own = bf1_r;     // z0 = W_f1 * 0 + b_f1
    float y_own = 0.f;       // y0 = W_h * 0
    u32 eA = 0, eB = 0, eC = 0, eD = 0;
    float4 wa[16], wb[16];

    #pragma unroll 1
    for (int i = 1; i < TSTEPS; ++i) {
        const float dt = (t[i] - t[i - 1]) * 0.25f;

        // ---- phase 1: publish u1 -> QA; consume: z,y += dt(M/P u1 + c)
        ++eA;
        if (seg == 0) astore(&QA[row], pack(eA, tanhf(z_own)));
        float4 xr[8], wir[8];                  // W_in @ x_i: loads hide under poll
        {
            const float4* xp = reinterpret_cast<const float4*>(x + (size_t)i * INP);
            const float4* wp = reinterpret_cast<const float4*>(W_in + (size_t)row * INP);
            #pragma unroll
            for (int j = 0; j < 8; ++j) { xr[j] = xp[j * 16 + seg]; wir[j] = wp[j * 16 + seg]; }
        }
        pref16(wa, Mw); pref16(wb, Pw);
        stage(QA, eA);
        float winx;
        {
            float a_ = 0.f;
            #pragma unroll
            for (int j = 0; j < 8; ++j) {
                a_ = fmaf(wir[j].x, xr[j].x, a_); a_ = fmaf(wir[j].y, xr[j].y, a_);
                a_ = fmaf(wir[j].z, xr[j].z, a_); a_ = fmaf(wir[j].w, xr[j].w, a_);
            }
            winx = reduce16(a_);
        }
        {
            const float md = reduce16(dot16(wa));
            const float pd = reduce16(dot16(wb));
            if (seg == 0) { z_own = fmaf(dt, md + c1_own, z_own);
                            y_own = fmaf(dt, pd + c2_own, y_own); }
        }

        // ---- phase 2: publish u2 -> QB
        ++eB;
        if (seg == 0) astore(&QB[row], pack(eB, tanhf(z_own)));
        pref16(wa, Mw); pref16(wb, Pw);
        stage(QB, eB);
        {
            const float md = reduce16(dot16(wa));
            const float pd = reduce16(dot16(wb));
            if (seg == 0) { z_own = fmaf(dt, md + c1_own, z_own);
                            y_own = fmaf(dt, pd + c2_own, y_own); }
        }

        // ---- phase 3: publish u3 -> QA
        ++eA;
        if (seg == 0) astore(&QA[row], pack(eA, tanhf(z_own)));
        pref16(wa, Mw); pref16(wb, Pw);
        stage(QA, eA);
        {
            const float md = reduce16(dot16(wa));
            const float pd = reduce16(dot16(wb));
            if (seg == 0) { z_own = fmaf(dt, md + c1_own, z_own);
                            y_own = fmaf(dt, pd + c2_own, y_own); }
        }

        // ---- phase 4: publish u4 -> QB; consume: y4 only (z4 dead), then a
        ++eB;
        if (seg == 0) astore(&QB[row], pack(eB, tanhf(z_own)));
        pref16(wb, Pw);
        stage(QB, eB);
        float a_val = 0.f;
        {
            const float pd = reduce16(dot16(wb));
            if (seg == 0) {
                const float y4 = fmaf(dt, pd + c2_own, y_own);
                a_val = tanhf(y4 + winx + bih_r);
            }
        }

        // ---- phase 5: publish a -> QC; consume: h' = tanh(W_h2 a + b_h2)
        ++eC;
        if (seg == 0) astore(&QC[row], pack(eC, a_val));
        pref16(wa, W_h2);
        stage(QC, eC);
        float h_new = 0.f;
        {
            const float hd = reduce16(dot16(wa));
            if (seg == 0) h_new = tanhf(hd + bh2_r);
        }

        // ---- phase 6: publish h' -> QD; consume: z0' = W_f1 h' + b_f1, y0' = W_h h'
        ++eD;
        if (seg == 0) astore(&QD[row], pack(eD, h_new));
        pref16(wa, W_f1);
        stage(QD, eD);
        {
            const float zd = reduce16(dot16(wa));
            pref16(wb, W_h);
            const float yd = reduce16(dot16(wb));
            if (seg == 0) { z_own = zd + bf1_r; y_own = yd; }
        }
    }

    // ---- decoder: lds still holds h_T from the last phase-6 stage
    {
        const int rl = tid >> 6, s2 = tid & 63;
        const int orow = wg * 4 + rl;
        const float4* wd = reinterpret_cast<const float4*>(W_dec + (size_t)orow * HDIM);
        float acc = 0.f;
        #pragma unroll
        for (int j = 0; j < 4; ++j) {
            const float4 w = wd[j * 64 + s2];
            const float4 v = *reinterpret_cast<const float4*>(lds + j * 256 + s2 * 4);
            acc = fmaf(w.x, v.x, acc); acc = fmaf(w.y, v.y, acc);
            acc = fmaf(w.z, v.z, acc); acc = fmaf(w.w, v.w, acc);
        }
        #pragma unroll
        for (int off = 32; off; off >>= 1) acc += __shfl_down(acc, off, 64);
        if (s2 == 0) out[orow] = acc + b_dec[orow];
    }
}

extern "C" void kernel_launch(void* const* d_in, const int* in_sizes, int n_in,
                              void* d_out, int out_size, void* d_ws, size_t ws_size,
                              hipStream_t stream) {
    const float* t     = (const float*)d_in[0];
    const float* x     = (const float*)d_in[1];
    const float* W_in  = (const float*)d_in[2];
    const float* b_in  = (const float*)d_in[3];
    const float* W_h   = (const float*)d_in[4];
    const float* b_h   = (const float*)d_in[5];
    const float* W_h2  = (const float*)d_in[6];
    const float* b_h2  = (const float*)d_in[7];
    const float* W_f1  = (const float*)d_in[8];
    const float* b_f1  = (const float*)d_in[9];
    const float* W_f2  = (const float*)d_in[10];
    const float* b_f2  = (const float*)d_in[11];
    const float* W_dec = (const float*)d_in[12];
    const float* b_dec = (const float*)d_in[13];
    float* out = (float*)d_out;

    // ws layout: M (4MB) | P (4MB) | QA,QB,QC,QD (4 x 8KB)
    unsigned char* ws = (unsigned char*)d_ws;
    float* Mw = (float*)(ws);
    float* Pw = (float*)(ws + (size_t)4 * 1024 * 1024);
    u64*   QA = (u64*)(ws + (size_t)8 * 1024 * 1024);
    u64*   QB = QA + HDIM;
    u64*   QC = QB + HDIM;
    u64*   QD = QC + HDIM;

    // precompute M = W_f1 @ W_f2, P = W_h @ W_f2 (every call; deterministic)
    mm1024<<<dim3(16, 16), 256, 0, stream>>>(W_f1, W_f2, Mw);
    mm1024<<<dim3(16, 16), 256, 0, stream>>>(W_h,  W_f2, Pw);

    // reset epoch tags to 0 (first expected tag is 1); must happen every call
    hipMemsetAsync(ws + (size_t)8 * 1024 * 1024, 0, 4 * HDIM * sizeof(u64), stream);

    ode_rnn_persistent<<<dim3(NWG), dim3(BLK), 0, stream>>>(
        t, x, W_in, b_in, W_h, b_h, W_h2, b_h2, W_f1, b_f1, b_f2,
        W_dec, b_dec, Mw, Pw, out, QA, QB, QC, QD);
}